// Round 1
// baseline (176.574 us; speedup 1.0000x reference)
//
#include <hip/hip_runtime.h>
#include <hip/hip_bf16.h>

typedef _Float16 f16;
typedef f16 f16x8 __attribute__((ext_vector_type(8)));
typedef f16 f16x2 __attribute__((ext_vector_type(2)));
typedef float f32x4 __attribute__((ext_vector_type(4)));

#define IN_F 256
#define OUT_F 128

// ---------------- W transpose + fp16 convert: Wt[n][k] = W[k][n] ----------------
__global__ __launch_bounds__(256) void prep_w(const float* __restrict__ W,
                                              f16* __restrict__ Wt) {
    int i = blockIdx.x * 256 + threadIdx.x;   // i over 256*128
    int k = i >> 7;          // row of W (0..255)
    int n = i & 127;         // col of W (0..127)
    Wt[n * IN_F + k] = (f16)W[i];
}

// ---------------- segment bounds from sorted edge_dst ----------------
__global__ __launch_bounds__(256) void seg_bounds(const int* __restrict__ dst,
                                                  int* __restrict__ rs,
                                                  int* __restrict__ re, int E) {
    int i = blockIdx.x * 256 + threadIdx.x;
    if (i >= E) return;
    int d = dst[i];
    if (i == 0 || dst[i - 1] != d) rs[d] = i;
    if (i == E - 1 || dst[i + 1] != d) re[d] = i + 1;
}

// ---------------- GEMM: S[m][n] = sum_k X[m][k] * W[k][n], fp16 MFMA ----------------
// block = 256 threads (4 waves), tile 128(M) x 128(N); wave tile 64x64.
// Fragments loaded straight from global (L1/L2 cached), no LDS this round.
__global__ __launch_bounds__(256) void gemm_xw(const float* __restrict__ X,
                                               const f16* __restrict__ Wt,
                                               f16* __restrict__ S, int M) {
    const int w = threadIdx.x >> 6;
    const int l = threadIdx.x & 63;
    const int r = l & 15;
    const int khi = l >> 4;
    const int wm = w >> 1, wn = w & 1;
    const int mbase = blockIdx.x * 128 + wm * 64;
    const int nbase = wn * 64;

    f32x4 acc[4][4] = {};

    #pragma unroll
    for (int ks = 0; ks < 8; ++ks) {           // K = 256 in steps of 32
        const int k0 = ks * 32 + khi * 8;
        f16x8 a[4], b[4];
        #pragma unroll
        for (int m = 0; m < 4; ++m) {
            int row = mbase + m * 16 + r;
            row = row < M ? row : M - 1;       // clamp (last block tail)
            const float4* p = (const float4*)(X + (size_t)row * IN_F + k0);
            float4 x0 = p[0], x1 = p[1];
            a[m][0] = (f16)x0.x; a[m][1] = (f16)x0.y;
            a[m][2] = (f16)x0.z; a[m][3] = (f16)x0.w;
            a[m][4] = (f16)x1.x; a[m][5] = (f16)x1.y;
            a[m][6] = (f16)x1.z; a[m][7] = (f16)x1.w;
        }
        #pragma unroll
        for (int n = 0; n < 4; ++n) {
            int col = nbase + n * 16 + r;
            b[n] = *(const f16x8*)(Wt + (size_t)col * IN_F + k0);
        }
        #pragma unroll
        for (int m = 0; m < 4; ++m)
            #pragma unroll
            for (int n = 0; n < 4; ++n)
                acc[m][n] = __builtin_amdgcn_mfma_f32_16x16x32_f16(a[m], b[n], acc[m][n], 0, 0, 0);
    }

    // C/D layout: D[(l>>4)*4 + i][l&15]
    #pragma unroll
    for (int m = 0; m < 4; ++m) {
        int row0 = mbase + m * 16 + khi * 4;
        #pragma unroll
        for (int i = 0; i < 4; ++i) {
            int row = row0 + i;
            if (row < M) {
                #pragma unroll
                for (int n = 0; n < 4; ++n)
                    S[(size_t)row * OUT_F + nbase + n * 16 + r] = (f16)acc[m][n][i];
            }
        }
    }
}

// ---------------- aggregation: out[d] = tanh(bias + sum_e val[e]*S[src[e]]) ----------------
// one wave per node; lane owns features (2l, 2l+1)
__global__ __launch_bounds__(256) void aggregate(const f16* __restrict__ S,
                                                 const int* __restrict__ rs,
                                                 const int* __restrict__ re,
                                                 const int* __restrict__ esrc,
                                                 const float* __restrict__ eval,
                                                 const float* __restrict__ bias,
                                                 float* __restrict__ out, int N) {
    const int wave = threadIdx.x >> 6;
    const int lane = threadIdx.x & 63;
    const int node = blockIdx.x * 4 + wave;
    if (node >= N) return;

    const int s = rs[node];
    const int e = re[node];

    float accx = 0.f, accy = 0.f;
    for (int base = s; base < e; base += 64) {
        const int cnt = min(64, e - base);
        int my_src = 0; float my_val = 0.f;
        if (lane < cnt) { my_src = esrc[base + lane]; my_val = eval[base + lane]; }
        for (int i = 0; i < cnt; ++i) {
            int se = __shfl(my_src, i);
            float ve = __shfl(my_val, i);
            f16x2 h = ((const f16x2*)(S + (size_t)se * OUT_F))[lane];
            accx += ve * (float)h[0];
            accy += ve * (float)h[1];
        }
    }

    float2 b = ((const float2*)bias)[lane];
    float2 o;
    o.x = tanhf(accx + b.x);
    o.y = tanhf(accy + b.y);
    ((float2*)out)[(size_t)node * 64 + lane] = o;
}

extern "C" void kernel_launch(void* const* d_in, const int* in_sizes, int n_in,
                              void* d_out, int out_size, void* d_ws, size_t ws_size,
                              hipStream_t stream) {
    const float* X    = (const float*)d_in[0];
    const float* W    = (const float*)d_in[1];
    const float* bias = (const float*)d_in[2];
    const int*   esrc = (const int*)d_in[3];
    const int*   edst = (const int*)d_in[4];
    const float* eval = (const float*)d_in[5];
    float* out = (float*)d_out;

    const int N = in_sizes[0] / IN_F;      // 100000
    const int E = in_sizes[3];             // 1600000

    // workspace layout
    char* ws = (char*)d_ws;
    f16* Wt = (f16*)ws;                                   // 128*256*2 = 64 KB
    f16* S  = (f16*)(ws + 65536);                         // N*128*2 = 25.6 MB
    int* rs = (int*)(ws + 65536 + (size_t)N * OUT_F * 2); // N ints
    int* re = rs + N;

    hipMemsetAsync(rs, 0, 2 * (size_t)N * sizeof(int), stream);
    prep_w<<<(IN_F * OUT_F) / 256, 256, 0, stream>>>(W, Wt);
    seg_bounds<<<(E + 255) / 256, 256, 0, stream>>>(edst, rs, re, E);
    gemm_xw<<<(N + 127) / 128, 256, 0, stream>>>(X, Wt, S, N);
    aggregate<<<(N + 3) / 4, 256, 0, stream>>>(S, rs, re, esrc, eval, bias, out, N);
}

// Round 2
// 133.925 us; speedup vs baseline: 1.3185x; 1.3185x over previous
//
#include <hip/hip_runtime.h>
#include <hip/hip_bf16.h>

typedef _Float16 f16;
typedef f16 f16x8 __attribute__((ext_vector_type(8)));
typedef f16 f16x2 __attribute__((ext_vector_type(2)));
typedef float f32x4 __attribute__((ext_vector_type(4)));

#define IN_F 256
#define OUT_F 128

// ---------------- W transpose + fp16 convert: Wt[n][k] = W[k][n] ----------------
__global__ __launch_bounds__(256) void prep_w(const float* __restrict__ W,
                                              f16* __restrict__ Wt) {
    int i = blockIdx.x * 256 + threadIdx.x;   // i over 256*128
    int k = i >> 7;          // row of W (0..255)
    int n = i & 127;         // col of W (0..127)
    Wt[n * IN_F + k] = (f16)W[i];
}

// ---------------- segment bounds from sorted edge_dst ----------------
__global__ __launch_bounds__(256) void seg_bounds(const int* __restrict__ dst,
                                                  int* __restrict__ rs,
                                                  int* __restrict__ re, int E) {
    int i = blockIdx.x * 256 + threadIdx.x;
    if (i >= E) return;
    int d = dst[i];
    if (i == 0 || dst[i - 1] != d) rs[d] = i;
    if (i == E - 1 || dst[i + 1] != d) re[d] = i + 1;
}

// ---------------- GEMM: S[m][n] = sum_k X[m][k] * W[k][n], fp16 MFMA ----------------
// block = 256 threads (4 waves), tile 128(M) x 128(N); wave tile 64x64.
__global__ __launch_bounds__(256) void gemm_xw(const float* __restrict__ X,
                                               const f16* __restrict__ Wt,
                                               f16* __restrict__ S, int M) {
    const int w = threadIdx.x >> 6;
    const int l = threadIdx.x & 63;
    const int r = l & 15;
    const int khi = l >> 4;
    const int wm = w >> 1, wn = w & 1;
    const int mbase = blockIdx.x * 128 + wm * 64;
    const int nbase = wn * 64;

    f32x4 acc[4][4] = {};

    #pragma unroll
    for (int ks = 0; ks < 8; ++ks) {           // K = 256 in steps of 32
        const int k0 = ks * 32 + khi * 8;
        f16x8 a[4], b[4];
        #pragma unroll
        for (int m = 0; m < 4; ++m) {
            int row = mbase + m * 16 + r;
            row = row < M ? row : M - 1;       // clamp (last block tail)
            const float4* p = (const float4*)(X + (size_t)row * IN_F + k0);
            float4 x0 = p[0], x1 = p[1];
            a[m][0] = (f16)x0.x; a[m][1] = (f16)x0.y;
            a[m][2] = (f16)x0.z; a[m][3] = (f16)x0.w;
            a[m][4] = (f16)x1.x; a[m][5] = (f16)x1.y;
            a[m][6] = (f16)x1.z; a[m][7] = (f16)x1.w;
        }
        #pragma unroll
        for (int n = 0; n < 4; ++n) {
            int col = nbase + n * 16 + r;
            b[n] = *(const f16x8*)(Wt + (size_t)col * IN_F + k0);
        }
        #pragma unroll
        for (int m = 0; m < 4; ++m)
            #pragma unroll
            for (int n = 0; n < 4; ++n)
                acc[m][n] = __builtin_amdgcn_mfma_f32_16x16x32_f16(a[m], b[n], acc[m][n], 0, 0, 0);
    }

    // C/D layout: D[(l>>4)*4 + i][l&15]
    #pragma unroll
    for (int m = 0; m < 4; ++m) {
        int row0 = mbase + m * 16 + khi * 4;
        #pragma unroll
        for (int i = 0; i < 4; ++i) {
            int row = row0 + i;
            if (row < M) {
                #pragma unroll
                for (int n = 0; n < 4; ++n)
                    S[(size_t)row * OUT_F + nbase + n * 16 + r] = (f16)acc[m][n][i];
            }
        }
    }
}

// ---------------- aggregation: out[d] = tanh(bias + sum_e val[e]*S[src[e]]) ----------------
// one wave per node; lane owns features (2l, 2l+1).
// Inner edge loop unrolled x8 so 8 independent row-gathers are in flight
// (latency-bound -> pipelined; S is L2/L3-resident).
__global__ __launch_bounds__(256) void aggregate(const f16* __restrict__ S,
                                                 const int* __restrict__ rs,
                                                 const int* __restrict__ re,
                                                 const int* __restrict__ esrc,
                                                 const float* __restrict__ eval,
                                                 const float* __restrict__ bias,
                                                 float* __restrict__ out, int N) {
    const int wave = threadIdx.x >> 6;
    const int lane = threadIdx.x & 63;
    const int node = blockIdx.x * 4 + wave;
    if (node >= N) return;

    const int s = rs[node];
    const int e = re[node];

    float accx = 0.f, accy = 0.f;
    for (int base = s; base < e; base += 64) {
        const int cnt = min(64, e - base);
        int my_src = 0; float my_val = 0.f;
        if (lane < cnt) { my_src = esrc[base + lane]; my_val = eval[base + lane]; }

        int i = 0;
        for (; i + 8 <= cnt; i += 8) {
            f16x2 h[8];
            float v[8];
            #pragma unroll
            for (int j = 0; j < 8; ++j) {
                int se = __shfl(my_src, i + j);
                v[j] = __shfl(my_val, i + j);
                h[j] = ((const f16x2*)(S + (size_t)se * OUT_F))[lane];
            }
            #pragma unroll
            for (int j = 0; j < 8; ++j) {
                accx += v[j] * (float)h[j][0];
                accy += v[j] * (float)h[j][1];
            }
        }
        // tail (degree % 8)
        for (; i < cnt; ++i) {
            int se = __shfl(my_src, i);
            float ve = __shfl(my_val, i);
            f16x2 h = ((const f16x2*)(S + (size_t)se * OUT_F))[lane];
            accx += ve * (float)h[0];
            accy += ve * (float)h[1];
        }
    }

    float2 b = ((const float2*)bias)[lane];
    float2 o;
    o.x = tanhf(accx + b.x);
    o.y = tanhf(accy + b.y);
    ((float2*)out)[(size_t)node * 64 + lane] = o;
}

extern "C" void kernel_launch(void* const* d_in, const int* in_sizes, int n_in,
                              void* d_out, int out_size, void* d_ws, size_t ws_size,
                              hipStream_t stream) {
    const float* X    = (const float*)d_in[0];
    const float* W    = (const float*)d_in[1];
    const float* bias = (const float*)d_in[2];
    const int*   esrc = (const int*)d_in[3];
    const int*   edst = (const int*)d_in[4];
    const float* eval = (const float*)d_in[5];
    float* out = (float*)d_out;

    const int N = in_sizes[0] / IN_F;      // 100000
    const int E = in_sizes[3];             // 1600000

    // workspace layout
    char* ws = (char*)d_ws;
    f16* Wt = (f16*)ws;                                   // 128*256*2 = 64 KB
    f16* S  = (f16*)(ws + 65536);                         // N*128*2 = 25.6 MB
    int* rs = (int*)(ws + 65536 + (size_t)N * OUT_F * 2); // N ints
    int* re = rs + N;

    hipMemsetAsync(rs, 0, 2 * (size_t)N * sizeof(int), stream);
    prep_w<<<(IN_F * OUT_F) / 256, 256, 0, stream>>>(W, Wt);
    seg_bounds<<<(E + 255) / 256, 256, 0, stream>>>(edst, rs, re, E);
    gemm_xw<<<(N + 127) / 128, 256, 0, stream>>>(X, Wt, S, N);
    aggregate<<<(N + 3) / 4, 256, 0, stream>>>(S, rs, re, esrc, eval, bias, out, N);
}

// Round 3
// 131.992 us; speedup vs baseline: 1.3378x; 1.0147x over previous
//
#include <hip/hip_runtime.h>
#include <hip/hip_bf16.h>

typedef _Float16 f16;
typedef f16 f16x8 __attribute__((ext_vector_type(8)));
typedef f16 f16x2 __attribute__((ext_vector_type(2)));
typedef float f32x4 __attribute__((ext_vector_type(4)));

#define IN_F 256
#define OUT_F 128

// ---------------- W transpose + fp16 convert: Wt[n][k] = W[k][n] ----------------
__global__ __launch_bounds__(256) void prep_w(const float* __restrict__ W,
                                              f16* __restrict__ Wt) {
    int i = blockIdx.x * 256 + threadIdx.x;   // i over 256*128
    int k = i >> 7;          // row of W (0..255)
    int n = i & 127;         // col of W (0..127)
    Wt[n * IN_F + k] = (f16)W[i];
}

// ---------------- segment bounds from sorted edge_dst ----------------
__global__ __launch_bounds__(256) void seg_bounds(const int* __restrict__ dst,
                                                  int* __restrict__ rs,
                                                  int* __restrict__ re, int E) {
    int i = blockIdx.x * 256 + threadIdx.x;
    if (i >= E) return;
    int d = dst[i];
    if (i == 0 || dst[i - 1] != d) rs[d] = i;
    if (i == E - 1 || dst[i + 1] != d) re[d] = i + 1;
}

// ---------------- GEMM: S[m][n] = sum_k X[m][k] * W[k][n], fp16 MFMA ----------------
__global__ __launch_bounds__(256) void gemm_xw(const float* __restrict__ X,
                                               const f16* __restrict__ Wt,
                                               f16* __restrict__ S, int M) {
    const int w = threadIdx.x >> 6;
    const int l = threadIdx.x & 63;
    const int r = l & 15;
    const int khi = l >> 4;
    const int wm = w >> 1, wn = w & 1;
    const int mbase = blockIdx.x * 128 + wm * 64;
    const int nbase = wn * 64;

    f32x4 acc[4][4] = {};

    #pragma unroll
    for (int ks = 0; ks < 8; ++ks) {           // K = 256 in steps of 32
        const int k0 = ks * 32 + khi * 8;
        f16x8 a[4], b[4];
        #pragma unroll
        for (int m = 0; m < 4; ++m) {
            int row = mbase + m * 16 + r;
            row = row < M ? row : M - 1;       // clamp (last block tail)
            const float4* p = (const float4*)(X + (size_t)row * IN_F + k0);
            float4 x0 = p[0], x1 = p[1];
            a[m][0] = (f16)x0.x; a[m][1] = (f16)x0.y;
            a[m][2] = (f16)x0.z; a[m][3] = (f16)x0.w;
            a[m][4] = (f16)x1.x; a[m][5] = (f16)x1.y;
            a[m][6] = (f16)x1.z; a[m][7] = (f16)x1.w;
        }
        #pragma unroll
        for (int n = 0; n < 4; ++n) {
            int col = nbase + n * 16 + r;
            b[n] = *(const f16x8*)(Wt + (size_t)col * IN_F + k0);
        }
        #pragma unroll
        for (int m = 0; m < 4; ++m)
            #pragma unroll
            for (int n = 0; n < 4; ++n)
                acc[m][n] = __builtin_amdgcn_mfma_f32_16x16x32_f16(a[m], b[n], acc[m][n], 0, 0, 0);
    }

    // C/D layout: D[(l>>4)*4 + i][l&15]
    #pragma unroll
    for (int m = 0; m < 4; ++m) {
        int row0 = mbase + m * 16 + khi * 4;
        #pragma unroll
        for (int i = 0; i < 4; ++i) {
            int row = row0 + i;
            if (row < M) {
                #pragma unroll
                for (int n = 0; n < 4; ++n)
                    S[(size_t)row * OUT_F + nbase + n * 16 + r] = (f16)acc[m][n][i];
            }
        }
    }
}

// ---------------- aggregation: out[d] = tanh(bias + sum_e val[e]*S[src[e]]) ----------------
// One wave per node. Lane l: group g = l>>4 handles edges (idx%4)==g,
// position p = l&15 owns features 8p..8p+7 (16 B of the 256 B row).
// One global_load_dwordx4 per lane gathers 4 full edge rows per wave;
// unroll x4 -> 16 edges / 4 independent gathers in flight.
// Edge src/val via direct (L1-hot, 4-address broadcast) loads -> no bpermute
// in the hot loop. Tail is branch-free: clamp index, zero the weight.
__global__ __launch_bounds__(256) void aggregate(const f16* __restrict__ S,
                                                 const int* __restrict__ rs,
                                                 const int* __restrict__ re,
                                                 const int* __restrict__ esrc,
                                                 const float* __restrict__ eval,
                                                 const float* __restrict__ bias,
                                                 float* __restrict__ out, int N) {
    const int wave = threadIdx.x >> 6;
    const int lane = threadIdx.x & 63;
    const int node = blockIdx.x * 4 + wave;
    if (node >= N) return;

    const int g = lane >> 4;
    const int p = lane & 15;

    const int s = rs[node];
    const int e = re[node];

    float acc[8] = {};

    for (int base = s; base < e; base += 16) {
        int   se[4];
        float ve[4];
        #pragma unroll
        for (int j = 0; j < 4; ++j) {
            int ei  = base + j * 4 + g;
            int eic = min(ei, e - 1);
            se[j] = esrc[eic];
            ve[j] = eval[eic];
            if (ei >= e) ve[j] = 0.f;
        }
        f16x8 h[4];
        #pragma unroll
        for (int j = 0; j < 4; ++j)
            h[j] = *(const f16x8*)(S + (size_t)se[j] * OUT_F + p * 8);
        #pragma unroll
        for (int j = 0; j < 4; ++j)
            #pragma unroll
            for (int q = 0; q < 8; ++q)
                acc[q] += ve[j] * (float)h[j][q];
    }

    // fold the 4 edge-groups: every lane ends with full sums for its p-slice
    #pragma unroll
    for (int q = 0; q < 8; ++q) {
        acc[q] += __shfl_xor(acc[q], 16);
        acc[q] += __shfl_xor(acc[q], 32);
    }

    // lanes 0..31 write: lane = half*16 + p writes features 8p+4*half .. +3
    if (lane < 32) {
        const int half = lane >> 4;   // 0 or 1
        const int f0 = 8 * p + 4 * half;
        float4 bb = *(const float4*)(bias + f0);
        float4 o;
        o.x = tanhf(acc[4 * half + 0] + bb.x);
        o.y = tanhf(acc[4 * half + 1] + bb.y);
        o.z = tanhf(acc[4 * half + 2] + bb.z);
        o.w = tanhf(acc[4 * half + 3] + bb.w);
        *(float4*)(out + (size_t)node * OUT_F + f0) = o;
    }
}

extern "C" void kernel_launch(void* const* d_in, const int* in_sizes, int n_in,
                              void* d_out, int out_size, void* d_ws, size_t ws_size,
                              hipStream_t stream) {
    const float* X    = (const float*)d_in[0];
    const float* W    = (const float*)d_in[1];
    const float* bias = (const float*)d_in[2];
    const int*   esrc = (const int*)d_in[3];
    const int*   edst = (const int*)d_in[4];
    const float* eval = (const float*)d_in[5];
    float* out = (float*)d_out;

    const int N = in_sizes[0] / IN_F;      // 100000
    const int E = in_sizes[3];             // 1600000

    // workspace layout
    char* ws = (char*)d_ws;
    f16* Wt = (f16*)ws;                                   // 128*256*2 = 64 KB
    f16* S  = (f16*)(ws + 65536);                         // N*128*2 = 25.6 MB
    int* rs = (int*)(ws + 65536 + (size_t)N * OUT_F * 2); // N ints
    int* re = rs + N;

    hipMemsetAsync(rs, 0, 2 * (size_t)N * sizeof(int), stream);
    prep_w<<<(IN_F * OUT_F) / 256, 256, 0, stream>>>(W, Wt);
    seg_bounds<<<(E + 255) / 256, 256, 0, stream>>>(edst, rs, re, E);
    gemm_xw<<<(N + 127) / 128, 256, 0, stream>>>(X, Wt, S, N);
    aggregate<<<(N + 3) / 4, 256, 0, stream>>>(S, rs, re, esrc, eval, bias, out, N);
}

// Round 4
// 114.376 us; speedup vs baseline: 1.5438x; 1.1540x over previous
//
#include <hip/hip_runtime.h>
#include <hip/hip_bf16.h>

typedef _Float16 f16;
typedef f16 f16x8 __attribute__((ext_vector_type(8)));
typedef f16 f16x4 __attribute__((ext_vector_type(4)));
typedef f16 f16x2 __attribute__((ext_vector_type(2)));
typedef float f32x4 __attribute__((ext_vector_type(4)));

#define IN_F 256
#define OUT_F 128
#define BK 64

// ---------------- W transpose + fp16 convert: Wt[n][k] = W[k][n] ----------------
__global__ __launch_bounds__(256) void prep_w(const float* __restrict__ W,
                                              f16* __restrict__ Wt) {
    int i = blockIdx.x * 256 + threadIdx.x;   // i over 256*128
    int k = i >> 7;          // row of W (0..255)
    int n = i & 127;         // col of W (0..127)
    Wt[n * IN_F + k] = (f16)W[i];
}

// ---------------- segment bounds from sorted edge_dst ----------------
__global__ __launch_bounds__(256) void seg_bounds(const int* __restrict__ dst,
                                                  int* __restrict__ rs,
                                                  int* __restrict__ re, int E) {
    int i = blockIdx.x * 256 + threadIdx.x;
    if (i >= E) return;
    int d = dst[i];
    if (i == 0 || dst[i - 1] != d) rs[d] = i;
    if (i == E - 1 || dst[i + 1] != d) re[d] = i + 1;
}

// ---------------- GEMM: S[m][n] = sum_k X[m][k] * W[k][n], fp16 MFMA ----------------
// 128x128 block tile, 4 waves as 2x2 (wave tile 64x64), K-step 64, double-
// buffered fp16 X tile in LDS (f32->f16 converted during reg-staging).
// XOR swizzle (row&7)<<3 on the fp16 tile kills the 128B-row-stride bank
// conflict (T2). T14 split: issue next tile's global loads BEFORE compute,
// cvt+ds_write after. Wt (64 KB) stays global/L2-hot.
__global__ __launch_bounds__(256) void gemm_xw(const float* __restrict__ X,
                                               const f16* __restrict__ Wt,
                                               f16* __restrict__ S, int M) {
    __shared__ f16 sx[2][128 * BK] __attribute__((aligned(16)));  // 2 x 16 KB

    const int w   = threadIdx.x >> 6;
    const int l   = threadIdx.x & 63;
    const int r   = l & 15;
    const int khi = l >> 4;
    const int wm = w >> 1, wn = w & 1;
    const int brow  = blockIdx.x * 128;
    const int mbase = wm * 64;
    const int nbase = wn * 64;

    // staging: wave w owns tile rows [w*32, w*32+32); lane covers 4 f32 cols
    const int srow = w * 32 + (l >> 4);   // + j*4
    const int scol = (l & 15) * 4;

    f32x4 acc[4][4] = {};
    float4 xv[8];

    // ---- prologue: stage K-step 0 into buf 0 ----
    #pragma unroll
    for (int j = 0; j < 8; ++j) {
        int rloc = srow + j * 4;
        int rg = brow + rloc; rg = rg < M ? rg : M - 1;
        xv[j] = *(const float4*)(X + (size_t)rg * IN_F + scol);
    }
    #pragma unroll
    for (int j = 0; j < 8; ++j) {
        int rloc = srow + j * 4;
        f16x4 hv = { (f16)xv[j].x, (f16)xv[j].y, (f16)xv[j].z, (f16)xv[j].w };
        *(f16x4*)&sx[0][rloc * BK + (scol ^ ((rloc & 7) << 3))] = hv;
    }
    __syncthreads();

    #pragma unroll
    for (int t = 0; t < 4; ++t) {
        // ---- issue next K-step's global loads (latency hidden under MFMA) ----
        if (t < 3) {
            const int k0 = (t + 1) * BK;
            #pragma unroll
            for (int j = 0; j < 8; ++j) {
                int rloc = srow + j * 4;
                int rg = brow + rloc; rg = rg < M ? rg : M - 1;
                xv[j] = *(const float4*)(X + (size_t)rg * IN_F + k0 + scol);
            }
        }
        // ---- compute from buf t&1 ----
        #pragma unroll
        for (int kk = 0; kk < 2; ++kk) {
            f16x8 a[4], b[4];
            const int sidx = (kk * 32 + khi * 8) ^ ((r & 7) << 3);
            #pragma unroll
            for (int m = 0; m < 4; ++m) {
                int arow = mbase + m * 16 + r;
                a[m] = *(const f16x8*)&sx[t & 1][arow * BK + sidx];
            }
            const int kg = t * BK + kk * 32 + khi * 8;
            #pragma unroll
            for (int n = 0; n < 4; ++n)
                b[n] = *(const f16x8*)(Wt + (size_t)(nbase + n * 16 + r) * IN_F + kg);
            #pragma unroll
            for (int m = 0; m < 4; ++m)
                #pragma unroll
                for (int n = 0; n < 4; ++n)
                    acc[m][n] = __builtin_amdgcn_mfma_f32_16x16x32_f16(a[m], b[n], acc[m][n], 0, 0, 0);
        }
        // ---- write next tile into the other buffer, then barrier ----
        if (t < 3) {
            #pragma unroll
            for (int j = 0; j < 8; ++j) {
                int rloc = srow + j * 4;
                f16x4 hv = { (f16)xv[j].x, (f16)xv[j].y, (f16)xv[j].z, (f16)xv[j].w };
                *(f16x4*)&sx[(t + 1) & 1][rloc * BK + (scol ^ ((rloc & 7) << 3))] = hv;
            }
        }
        __syncthreads();
    }

    // ---- epilogue: C/D layout D[(l>>4)*4 + i][l&15] ----
    #pragma unroll
    for (int m = 0; m < 4; ++m) {
        int row0 = brow + mbase + m * 16 + khi * 4;
        #pragma unroll
        for (int i = 0; i < 4; ++i) {
            int row = row0 + i;
            if (row < M) {
                #pragma unroll
                for (int n = 0; n < 4; ++n)
                    S[(size_t)row * OUT_F + nbase + n * 16 + r] = (f16)acc[m][n][i];
            }
        }
    }
}

// ---------------- aggregation: out[d] = tanh(bias + sum_e val[e]*S[src[e]]) ----------------
// (unchanged — at its beyond-L2 gather service wall, ~186 MB compulsory)
__global__ __launch_bounds__(256) void aggregate(const f16* __restrict__ S,
                                                 const int* __restrict__ rs,
                                                 const int* __restrict__ re,
                                                 const int* __restrict__ esrc,
                                                 const float* __restrict__ eval,
                                                 const float* __restrict__ bias,
                                                 float* __restrict__ out, int N) {
    const int wave = threadIdx.x >> 6;
    const int lane = threadIdx.x & 63;
    const int node = blockIdx.x * 4 + wave;
    if (node >= N) return;

    const int g = lane >> 4;
    const int p = lane & 15;

    const int s = rs[node];
    const int e = re[node];

    float acc[8] = {};

    for (int base = s; base < e; base += 16) {
        int   se[4];
        float ve[4];
        #pragma unroll
        for (int j = 0; j < 4; ++j) {
            int ei  = base + j * 4 + g;
            int eic = min(ei, e - 1);
            se[j] = esrc[eic];
            ve[j] = eval[eic];
            if (ei >= e) ve[j] = 0.f;
        }
        f16x8 h[4];
        #pragma unroll
        for (int j = 0; j < 4; ++j)
            h[j] = *(const f16x8*)(S + (size_t)se[j] * OUT_F + p * 8);
        #pragma unroll
        for (int j = 0; j < 4; ++j)
            #pragma unroll
            for (int q = 0; q < 8; ++q)
                acc[q] += ve[j] * (float)h[j][q];
    }

    #pragma unroll
    for (int q = 0; q < 8; ++q) {
        acc[q] += __shfl_xor(acc[q], 16);
        acc[q] += __shfl_xor(acc[q], 32);
    }

    if (lane < 32) {
        const int half = lane >> 4;   // 0 or 1
        const int f0 = 8 * p + 4 * half;
        float4 bb = *(const float4*)(bias + f0);
        float4 o;
        o.x = tanhf(acc[4 * half + 0] + bb.x);
        o.y = tanhf(acc[4 * half + 1] + bb.y);
        o.z = tanhf(acc[4 * half + 2] + bb.z);
        o.w = tanhf(acc[4 * half + 3] + bb.w);
        *(float4*)(out + (size_t)node * OUT_F + f0) = o;
    }
}

extern "C" void kernel_launch(void* const* d_in, const int* in_sizes, int n_in,
                              void* d_out, int out_size, void* d_ws, size_t ws_size,
                              hipStream_t stream) {
    const float* X    = (const float*)d_in[0];
    const float* W    = (const float*)d_in[1];
    const float* bias = (const float*)d_in[2];
    const int*   esrc = (const int*)d_in[3];
    const int*   edst = (const int*)d_in[4];
    const float* eval = (const float*)d_in[5];
    float* out = (float*)d_out;

    const int N = in_sizes[0] / IN_F;      // 100000
    const int E = in_sizes[3];             // 1600000

    // workspace layout
    char* ws = (char*)d_ws;
    f16* Wt = (f16*)ws;                                   // 128*256*2 = 64 KB
    f16* S  = (f16*)(ws + 65536);                         // N*128*2 = 25.6 MB
    int* rs = (int*)(ws + 65536 + (size_t)N * OUT_F * 2); // N ints
    int* re = rs + N;

    hipMemsetAsync(rs, 0, 2 * (size_t)N * sizeof(int), stream);
    prep_w<<<(IN_F * OUT_F) / 256, 256, 0, stream>>>(W, Wt);
    seg_bounds<<<(E + 255) / 256, 256, 0, stream>>>(edst, rs, re, E);
    gemm_xw<<<(N + 127) / 128, 256, 0, stream>>>(X, Wt, S, N);
    aggregate<<<(N + 3) / 4, 256, 0, stream>>>(S, rs, re, esrc, eval, bias, out, N);
}